// Round 10
// baseline (4406.530 us; speedup 1.0000x reference)
//
#include <hip/hip_runtime.h>
#include <stdint.h>

#define V_ 16000
#define E_ 512
#define H_ 1024
#define B_ 32
#define T_ 64
#define NG_ 3072        // 3*H rows per weight matrix
#define NR_ 6144        // virtual rows in gru gemm (ih + hh)
#define IHB_ 96         // ih tiles (3072/32)
#define TB_ 192         // gru tiles per K-slice
#define TPAD_ 8         // u64 stride per batch slot (64B line each)

typedef float f32x4 __attribute__((ext_vector_type(4)));
typedef unsigned long long u64;

__device__ __forceinline__ unsigned int fkey(float f) {
    unsigned int u = __float_as_uint(f);
    return (u & 0x80000000u) ? ~u : (u | 0x80000000u);
}

__global__ void init_kernel(const float* __restrict__ hidden,
                            float* __restrict__ h0, float* __restrict__ h1,
                            u64* __restrict__ tokpk) {
    int idx = blockIdx.x * blockDim.x + threadIdx.x;
    if (idx < B_ * H_) {
        h0[idx] = hidden[idx];
        h1[idx] = hidden[B_ * H_ + idx];
    }
    if (idx < T_ * B_ * TPAD_) tokpk[idx] = 0ull;
}

// ---------------------------------------------------------------------------
// Champion gemm_core, now with 2-ahead register prefetch (unroll-2, static
// register rotation). 32 rows x 32 batch x K tile, 512 threads. Each thread
// stages 1 W + 1 A row-chunk f32x4; XOR-swizzled LDS slots; ks = tid>>6
// (8-way K-split), 2 kk per chunk, acc[4][4]. REQUIRES nch >= 3 (callers
// use 4/8/16). Steady state: ds_write data was issued ~2 chunk-times ago.
// ---------------------------------------------------------------------------
__device__ __forceinline__ void gemm_core(
    const float* wp, const float* ap,
    int nch, float* lds, int tid, float acc[4][4])
{
    const int k4s = tid & 15;
    const int r   = tid >> 4;                       // 0..31
    const int dW  = (r << 6) + ((k4s ^ (r & 7)) << 2);
    const int ks   = tid >> 6;                      // 0..7
    const int lane = tid & 63;
    const int vg = lane >> 3, bg = lane & 7;
    float* lds0 = lds;
    float* lds1 = lds + 4096;

    auto ldW = [&](int c) { return *(const f32x4*)(wp + (c << 6) + (k4s << 2)); };
    auto ldA = [&](int c) { return *(const f32x4*)(ap + (c << 6) + (k4s << 2)); };
    auto stb = [&](float* b, f32x4 w, f32x4 a) {
        *(f32x4*)&b[dW] = w;
        *(f32x4*)&b[2048 + dW] = a;
    };
    auto compute = [&](const float* b) {
        const float* Wb = b;
        const float* Ab = b + 2048;
        #pragma unroll
        for (int kk = 0; kk < 2; kk++) {
            const int k4 = ks * 2 + kk;
            f32x4 ww[4], ha[4];
            #pragma unroll
            for (int vi = 0; vi < 4; vi++)
                ww[vi] = *(const f32x4*)&Wb[((vg + 8*vi) << 6) + ((k4 ^ vg) << 2)];
            #pragma unroll
            for (int j = 0; j < 4; j++)
                ha[j] = *(const f32x4*)&Ab[((bg + 8*j) << 6) + ((k4 ^ bg) << 2)];
            #pragma unroll
            for (int vi = 0; vi < 4; vi++)
                #pragma unroll
                for (int j = 0; j < 4; j++)
                    acc[vi][j] += ww[vi].x*ha[j].x + ww[vi].y*ha[j].y
                                + ww[vi].z*ha[j].z + ww[vi].w*ha[j].w;
        }
    };

    // prologue: chunk0 -> lds0; chunks 1,2 in flight (2-deep)
    { f32x4 w0 = ldW(0), a0 = ldA(0); stb(lds0, w0, a0); }
    f32x4 wA = ldW(1), aA = ldA(1);
    f32x4 wB = ldW(2), aB = ldA(2);
    __syncthreads();

    for (int c = 0; c < nch; c += 2) {
        // half 1: chunk c from lds0; writer (wA,aA) = chunk c+1
        f32x4 wN = wA, aN = aA;
        if (c + 3 < nch) { wN = ldW(c + 3); aN = ldA(c + 3); }
        compute(lds0);
        if (c + 1 < nch) stb(lds1, wA, aA);
        __syncthreads();
        if (c + 1 >= nch) break;
        wA = wN; aA = aN;                            // now holds c+3
        // half 2: chunk c+1 from lds1; writer (wB,aB) = chunk c+2
        f32x4 wM = wB, aM = aB;
        if (c + 4 < nch) { wM = ldW(c + 4); aM = ldA(c + 4); }
        compute(lds1);
        if (c + 2 < nch) stb(lds0, wB, aB);
        __syncthreads();
        wB = wM; aB = aM;                            // now holds c+4
    }
}

__device__ __forceinline__ void ks_reduce(float* lds, int tid,
                                          float acc[4][4], float tv[16])
{
    const int ks = tid >> 6, lane = tid & 63;
    float* dst = &lds[(ks * 64 + lane) * 17];       // [8][64][17]
    #pragma unroll
    for (int vi = 0; vi < 4; vi++)
        #pragma unroll
        for (int j = 0; j < 4; j++) dst[vi*4 + j] = acc[vi][j];
    __syncthreads();
    if (tid < 64) {
        #pragma unroll
        for (int c = 0; c < 16; c++) {
            float s = 0.f;
            #pragma unroll
            for (int k = 0; k < 8; k++) s += lds[(k*64 + tid)*17 + c];
            tv[c] = s;
        }
    }
}

// GRU GEMM, 2-way K-split: grid 384 = kslice(2) x tile(192). Tile<96: ih rows
// (W_ih, x); else hh rows (W_hh, h_prev). Each K-slice computes a partial over
// half of K, written to gbuf[kslice][b][n].
__global__ __launch_bounds__(512) void gemm_gru(
    const float* __restrict__ Wih, const float* __restrict__ Whh, int Kih,
    const float* __restrict__ xbase, int xld,
    const float* __restrict__ embed, const u64* __restrict__ tokprev,
    int t, int tmode,
    const float* __restrict__ hprev,
    float* __restrict__ gbuf)
{
    __shared__ float lds[8704];
    const int tid = threadIdx.x;
    const int blk0 = blockIdx.x;
    const int kslice = blk0 >= TB_ ? 1 : 0;
    const int blk = blk0 - kslice * TB_;
    const int r = tid >> 4;                         // 0..31

    const float *wp, *ap;
    int Kfull;
    if (blk < IHB_) {
        const int n0 = blk * 32;
        wp = Wih + (size_t)(n0 + r) * Kih;
        if (tmode) {
            int tok = 0;
            if (t > 0)
                tok = (int)(0xFFFFFFFFu -
                            (unsigned)(tokprev[(size_t)r * TPAD_] & 0xFFFFFFFFull));
            ap = embed + (size_t)tok * Kih;
        } else {
            ap = xbase + (size_t)r * xld;
        }
        Kfull = Kih;
    } else {
        const int n0 = (blk - IHB_) * 32;
        wp = Whh + (size_t)(n0 + r) * H_;
        ap = hprev + (size_t)r * H_;
        Kfull = H_;
    }
    const int koff = kslice * (Kfull >> 1);
    const int nch  = Kfull >> 7;                    // 4 or 8 chunks (half-K)

    float acc[4][4] = {};
    gemm_core(wp + koff, ap + koff, nch, lds, tid, acc);
    float tv[16];
    ks_reduce(lds, tid, acc, tv);
    if (tid < 64) {
        const int vgr = tid >> 3, bgr = tid & 7;
        const int nout0 = blk * 32;
        float* gout = gbuf + (size_t)kslice * B_ * NR_;
        #pragma unroll
        for (int vi = 0; vi < 4; vi++)
            #pragma unroll
            for (int j = 0; j < 4; j++)
                gout[(size_t)(bgr + 8*j) * NR_ + nout0 + vgr + 8*vi] = tv[vi*4+j];
    }
}

__global__ __launch_bounds__(256) void combine_kernel(
    const float* __restrict__ gbuf,
    const float* __restrict__ bih, const float* __restrict__ bhh,
    const float* __restrict__ hprev, float* __restrict__ hnew)
{
    const int idx = blockIdx.x * 256 + threadIdx.x;   // 0..32767
    const int b = idx >> 10, i = idx & 1023;
    const float* gb0 = gbuf + (size_t)b * NR_;
    const float* gb1 = gbuf + (size_t)(B_ + b) * NR_;
    const float gir = gb0[i]         + gb1[i];
    const float giz = gb0[H_ + i]    + gb1[H_ + i];
    const float gin = gb0[2*H_ + i]  + gb1[2*H_ + i];
    const float ghr = gb0[NG_ + i]        + gb1[NG_ + i];
    const float ghz = gb0[NG_ + H_ + i]   + gb1[NG_ + H_ + i];
    const float ghn = gb0[NG_ + 2*H_ + i] + gb1[NG_ + 2*H_ + i];
    const float Sr = gir + ghr + bih[i] + bhh[i];
    const float Sz = giz + ghz + bih[H_ + i] + bhh[H_ + i];
    const float rr = 1.f / (1.f + expf(-Sr));
    const float zz = 1.f / (1.f + expf(-Sz));
    const float nn = tanhf(gin + bih[2*H_ + i] + rr * (ghn + bhh[2*H_ + i]));
    const float hp = hprev[(size_t)b * H_ + i];
    hnew[(size_t)b * H_ + i] = (1.f - zz) * nn + zz * hp;
}

// Logits (32 vocab rows/block, grid 500, 512 thr) + bias + nt-store + argmax.
__global__ __launch_bounds__(512) void logits_kernel(
    const float* __restrict__ h1, const float* __restrict__ Wout,
    const float* __restrict__ bout, float* __restrict__ out_t,
    u64* __restrict__ tokpk_t)
{
    __shared__ float lds[10272];   // stream 8192 | red 8704, totl 1056, am 512
    const int tid = threadIdx.x;
    const int r = tid >> 4;                          // 0..31
    const int v0 = blockIdx.x * 32;
    const float* wp = Wout + (size_t)(v0 + r) * H_;
    const float* ap = h1 + (size_t)r * H_;

    float acc[4][4] = {};
    gemm_core(wp, ap, H_ >> 6, lds, tid, acc);
    float tv[16];
    ks_reduce(lds, tid, acc, tv);

    float* totl = lds + 8704;                        // [32][33]
    u64*   am   = (u64*)(lds + 8704 + 1056);         // [32][8]
    if (tid < 64) {
        const int vgr = tid >> 3, bgr = tid & 7;
        #pragma unroll
        for (int vi = 0; vi < 4; vi++) {
            const float bo = bout[v0 + vgr + 8*vi];
            #pragma unroll
            for (int j = 0; j < 4; j++) tv[vi*4+j] += bo;
        }
        #pragma unroll
        for (int vi = 0; vi < 4; vi++)
            #pragma unroll
            for (int j = 0; j < 4; j++)
                totl[(bgr + 8*j) * 33 + vgr + 8*vi] = tv[vi*4+j];
        #pragma unroll
        for (int j = 0; j < 4; j++) {
            u64 best = 0ull;
            #pragma unroll
            for (int vi = 0; vi < 4; vi++) {
                const int v = v0 + vgr + 8*vi;
                u64 p = ((u64)fkey(tv[vi*4+j]) << 32)
                      | (u64)(0xFFFFFFFFu - (unsigned)v);
                best = p > best ? p : best;
            }
            am[(bgr + 8*j) * 8 + vgr] = best;
        }
    }
    __syncthreads();
    if (tid < 64) {
        const int b = tid >> 1, half = tid & 1;
        #pragma unroll
        for (int q = 0; q < 4; q++) {
            f32x4 o;
            o.x = totl[b*33 + half*16 + q*4 + 0];
            o.y = totl[b*33 + half*16 + q*4 + 1];
            o.z = totl[b*33 + half*16 + q*4 + 2];
            o.w = totl[b*33 + half*16 + q*4 + 3];
            __builtin_nontemporal_store(
                o, (f32x4*)(out_t + (size_t)b * V_ + v0 + half*16 + q*4));
        }
    }
    if (tid < 32) {
        u64 best = 0ull;
        #pragma unroll
        for (int q = 0; q < 8; q++) {
            u64 p = am[tid*8 + q];
            best = p > best ? p : best;
        }
        atomicMax(&tokpk_t[(size_t)tid * TPAD_], best);
    }
}

extern "C" void kernel_launch(void* const* d_in, const int* in_sizes, int n_in,
                              void* d_out, int out_size, void* d_ws, size_t ws_size,
                              hipStream_t stream) {
    const float* hidden = (const float*)d_in[0];
    const float* embed  = (const float*)d_in[1];
    const float* Wih0   = (const float*)d_in[2];
    const float* Whh0   = (const float*)d_in[3];
    const float* bih0   = (const float*)d_in[4];
    const float* bhh0   = (const float*)d_in[5];
    const float* Wih1   = (const float*)d_in[6];
    const float* Whh1   = (const float*)d_in[7];
    const float* bih1   = (const float*)d_in[8];
    const float* bhh1   = (const float*)d_in[9];
    const float* Wout   = (const float*)d_in[10];
    const float* bout   = (const float*)d_in[11];
    float* out = (float*)d_out;

    const int BH = B_ * H_;
    float* ws = (float*)d_ws;
    float* h0buf = ws;                        // [2][B][H]
    float* h1buf = ws + 2 * BH;               // [2][B][H]
    float* gbuf  = ws + 4 * BH;               // [2][B][NR_]
    u64* tokpk = (u64*)(ws + 4 * BH + 2 * B_ * NR_);  // [T][B*TPAD_]

    init_kernel<<<128, 256, 0, stream>>>(hidden, h0buf, h1buf, tokpk);

    for (int t = 0; t < T_; t++) {
        const int rp = t & 1, wp = (t + 1) & 1;
        const u64* tokprev = tokpk + (size_t)(t > 0 ? t - 1 : 0) * B_ * TPAD_;

        gemm_gru<<<2 * TB_, 512, 0, stream>>>(
            Wih0, Whh0, E_, nullptr, 0, embed, tokprev, t, /*tmode=*/1,
            h0buf + (size_t)rp * BH, gbuf);
        combine_kernel<<<128, 256, 0, stream>>>(
            gbuf, bih0, bhh0, h0buf + (size_t)rp * BH, h0buf + (size_t)wp * BH);

        gemm_gru<<<2 * TB_, 512, 0, stream>>>(
            Wih1, Whh1, H_, h0buf + (size_t)wp * BH, H_, embed, tokprev, 0,
            /*tmode=*/0, h1buf + (size_t)rp * BH, gbuf);
        combine_kernel<<<128, 256, 0, stream>>>(
            gbuf, bih1, bhh1, h1buf + (size_t)rp * BH, h1buf + (size_t)wp * BH);

        logits_kernel<<<V_ / 32, 512, 0, stream>>>(
            h1buf + (size_t)wp * BH, Wout, bout,
            out + (size_t)t * B_ * V_, tokpk + (size_t)t * B_ * TPAD_);
    }
}

// Round 12
// 3943.995 us; speedup vs baseline: 1.1173x; 1.1173x over previous
//
#include <hip/hip_runtime.h>
#include <stdint.h>

#define V_ 16000
#define E_ 512
#define H_ 1024
#define B_ 32
#define T_ 64
#define NG_ 3072        // 3*H rows per weight matrix
#define NR_ 6144        // virtual rows in gru gemm (ih + hh)
#define TPAD_ 8         // u64 stride per batch token slot

typedef float f32x4 __attribute__((ext_vector_type(4)));
typedef unsigned long long u64;

__device__ __forceinline__ unsigned int fkey(float f) {
    unsigned int u = __float_as_uint(f);
    return (u & 0x80000000u) ? ~u : (u | 0x80000000u);
}

__global__ void init_kernel(const float* __restrict__ hidden,
                            float* __restrict__ h0, float* __restrict__ h1,
                            u64* __restrict__ tokpk) {
    int idx = blockIdx.x * blockDim.x + threadIdx.x;
    if (idx < B_ * H_) {
        h0[idx] = hidden[idx];
        h1[idx] = hidden[B_ * H_ + idx];
    }
    if (idx < T_ * B_ * TPAD_) tokpk[idx] = 0ull;
}

// ---------------------------------------------------------------------------
// 64-row x 32-batch streamed GEMM core, 256 threads, acc[8][8] (16 MAC per
// LDS read -- 2x the 4x4 tile; kernels are LDS-instruction-bound).
// Chunk = 64 k. LDS buffer = [W 64x64 | A 32x64] = 6144 floats, x2 (48KB).
// XOR-swizzled f32x4 slots (slot k4^(row&7)): conflict-free / broadcast reads.
// Staging: each thread loads 4 W + 2 A f32x4 per chunk (coalesced 1KB/wave),
// 1-chunk-ahead register prefetch. Compute: ks = tid>>5 (8-way K-split),
// pos = tid&31: rows rg+8vi (rg=pos>>2), batch bgp+4j (bgp=pos&3).
// ---------------------------------------------------------------------------
__device__ __forceinline__ void gemm_core64(
    const float* wq0, const float* wq1, const float* wq2, const float* wq3,
    const float* aq0, const float* aq1,
    int dW0, int dW1, int dW2, int dW3, int dA0, int dA1,
    int nch, float* lds, int tid, float acc[8][8])
{
    const int ks = tid >> 5, pos = tid & 31;
    const int rg = pos >> 2, bgp = pos & 3;

    f32x4 w0 = *(const f32x4*)wq0, w1 = *(const f32x4*)wq1;
    f32x4 w2 = *(const f32x4*)wq2, w3 = *(const f32x4*)wq3;
    f32x4 a0 = *(const f32x4*)aq0, a1 = *(const f32x4*)aq1;
    *(f32x4*)&lds[dW0] = w0; *(f32x4*)&lds[dW1] = w1;
    *(f32x4*)&lds[dW2] = w2; *(f32x4*)&lds[dW3] = w3;
    *(f32x4*)&lds[dA0] = a0; *(f32x4*)&lds[dA1] = a1;
    __syncthreads();

    int cur = 0;
    for (int c = 0; c < nch; c++) {
        if (c + 1 < nch) {
            const int o = (c + 1) << 6;
            w0 = *(const f32x4*)(wq0 + o); w1 = *(const f32x4*)(wq1 + o);
            w2 = *(const f32x4*)(wq2 + o); w3 = *(const f32x4*)(wq3 + o);
            a0 = *(const f32x4*)(aq0 + o); a1 = *(const f32x4*)(aq1 + o);
        }
        const float* Wb = &lds[cur * 6144];
        const float* Ab = Wb + 4096;
        #pragma unroll
        for (int kk = 0; kk < 2; kk++) {
            const int k4 = ks * 2 + kk;
            f32x4 ww[8], ha[8];
            #pragma unroll
            for (int vi = 0; vi < 8; vi++) {
                const int row = rg + 8 * vi;           // row&7 == rg
                ww[vi] = *(const f32x4*)&Wb[(row << 6) + ((k4 ^ rg) << 2)];
            }
            #pragma unroll
            for (int j = 0; j < 8; j++) {
                const int br = bgp + 4 * j;
                ha[j] = *(const f32x4*)&Ab[(br << 6) + ((k4 ^ (br & 7)) << 2)];
            }
            #pragma unroll
            for (int vi = 0; vi < 8; vi++)
                #pragma unroll
                for (int j = 0; j < 8; j++)
                    acc[vi][j] += ww[vi].x*ha[j].x + ww[vi].y*ha[j].y
                                + ww[vi].z*ha[j].z + ww[vi].w*ha[j].w;
        }
        if (c + 1 < nch) {
            float* L = &lds[(cur ^ 1) * 6144];
            *(f32x4*)&L[dW0] = w0; *(f32x4*)&L[dW1] = w1;
            *(f32x4*)&L[dW2] = w2; *(f32x4*)&L[dW3] = w3;
            *(f32x4*)&L[dA0] = a0; *(f32x4*)&L[dA1] = a1;
        }
        __syncthreads();
        cur ^= 1;
    }
}

// Reduce 8 ks partials ([8][32][68] overlay), then transpose into
// totl[32][68] at lds[0]: totl[b*68 + col] = full sum, col 0..63.
__device__ __forceinline__ void reduce_totl(float* lds, int tid, float acc[8][8])
{
    const int ks = tid >> 5, pos = tid & 31;
    {
        float* dst = &lds[(ks * 32 + pos) * 68];
        #pragma unroll
        for (int vi = 0; vi < 8; vi++) {
            f32x4 p0 = {acc[vi][0], acc[vi][1], acc[vi][2], acc[vi][3]};
            f32x4 p1 = {acc[vi][4], acc[vi][5], acc[vi][6], acc[vi][7]};
            *(f32x4*)&dst[vi * 8]     = p0;
            *(f32x4*)&dst[vi * 8 + 4] = p1;
        }
    }
    __syncthreads();
    const int vi2 = tid >> 5, pos2 = tid & 31;
    f32x4 s0 = {0.f, 0.f, 0.f, 0.f}, s1 = {0.f, 0.f, 0.f, 0.f};
    #pragma unroll
    for (int k = 0; k < 8; k++) {
        const float* src = &lds[(k * 32 + pos2) * 68 + vi2 * 8];
        s0 += *(const f32x4*)src;
        s1 += *(const f32x4*)(src + 4);
    }
    __syncthreads();
    const int row = (pos2 >> 2) + 8 * vi2;   // 0..63
    const int bb  = pos2 & 3;                // batch = bb + 4*j
    lds[(bb +  0) * 68 + row] = s0.x;
    lds[(bb +  4) * 68 + row] = s0.y;
    lds[(bb +  8) * 68 + row] = s0.z;
    lds[(bb + 12) * 68 + row] = s0.w;
    lds[(bb + 16) * 68 + row] = s1.x;
    lds[(bb + 20) * 68 + row] = s1.y;
    lds[(bb + 24) * 68 + row] = s1.z;
    lds[(bb + 28) * 68 + row] = s1.w;
    __syncthreads();
}

// GRU GEMM: grid 192 = kslice(2) x tile(96). Tiles 0..47: ih rows (Wih, x);
// 48..95: hh rows (Whh, hprev). 64 rows per tile; K halved per slice.
// BUGFIX r11: hh outputs land at NG_ + local row (combine expects hh at
// gbuf rows [NG_, NG_+3072)); r10 wrote them over the ih region.
__global__ __launch_bounds__(256) void gemm_gru(
    const float* __restrict__ Wih, const float* __restrict__ Whh, int Kih,
    const float* __restrict__ xbase, int xld,
    const float* __restrict__ embed, const u64* __restrict__ tokprev,
    int t, int tmode,
    const float* __restrict__ hprev,
    float* __restrict__ gbuf)
{
    __shared__ float lds[17408];
    const int tid = threadIdx.x;
    const int blk0 = blockIdx.x;
    const int kslice = blk0 >= 96 ? 1 : 0;
    const int tile = blk0 - kslice * 96;
    const int k4s = tid & 15;
    const int rr  = tid >> 4;                // 0..15

    const float* Wbase; int K, n0, nout;
    const float *ar0, *ar1;
    if (tile < 48) {
        n0 = tile * 64; nout = n0; Wbase = Wih; K = Kih;
        if (tmode) {
            int tok0 = 0, tok1 = 0;
            if (t > 0) {
                tok0 = (int)(0xFFFFFFFFu -
                       (unsigned)(tokprev[(size_t)rr * TPAD_] & 0xFFFFFFFFull));
                tok1 = (int)(0xFFFFFFFFu -
                       (unsigned)(tokprev[(size_t)(rr + 16) * TPAD_] & 0xFFFFFFFFull));
            }
            ar0 = embed + (size_t)tok0 * Kih;
            ar1 = embed + (size_t)tok1 * Kih;
        } else {
            ar0 = xbase + (size_t)rr * xld;
            ar1 = xbase + (size_t)(rr + 16) * xld;
        }
    } else {
        n0 = (tile - 48) * 64; nout = NG_ + n0; Wbase = Whh; K = H_;
        ar0 = hprev + (size_t)rr * H_;
        ar1 = hprev + (size_t)(rr + 16) * H_;
    }
    const int koff = kslice * (K >> 1);
    const int nch  = K >> 7;                 // 4 or 8 chunks

    const float *wq0, *wq1, *wq2, *wq3;
    int dW0, dW1, dW2, dW3;
    {
        const int r0 = rr, r1 = 16 + rr, r2 = 32 + rr, r3 = 48 + rr;
        wq0 = Wbase + (size_t)(n0 + r0) * K + koff + k4s * 4;
        wq1 = Wbase + (size_t)(n0 + r1) * K + koff + k4s * 4;
        wq2 = Wbase + (size_t)(n0 + r2) * K + koff + k4s * 4;
        wq3 = Wbase + (size_t)(n0 + r3) * K + koff + k4s * 4;
        dW0 = (r0 << 6) + ((k4s ^ (r0 & 7)) << 2);
        dW1 = (r1 << 6) + ((k4s ^ (r1 & 7)) << 2);
        dW2 = (r2 << 6) + ((k4s ^ (r2 & 7)) << 2);
        dW3 = (r3 << 6) + ((k4s ^ (r3 & 7)) << 2);
    }
    const float* aq0 = ar0 + koff + k4s * 4;
    const float* aq1 = ar1 + koff + k4s * 4;
    const int dA0 = 4096 + (rr << 6) + ((k4s ^ (rr & 7)) << 2);
    const int dA1 = 4096 + ((rr + 16) << 6) + ((k4s ^ (rr & 7)) << 2);

    float acc[8][8] = {};
    gemm_core64(wq0, wq1, wq2, wq3, aq0, aq1,
                dW0, dW1, dW2, dW3, dA0, dA1, nch, lds, tid, acc);
    reduce_totl(lds, tid, acc);

    // coalesced f32x4 stores: thread (b = tid>>3, seg = tid&7) -> 8 cols
    {
        const int b = tid >> 3, seg = tid & 7;
        float* gout = gbuf + (size_t)kslice * B_ * NR_
                    + (size_t)b * NR_ + nout + seg * 8;
        f32x4 x0 = *(f32x4*)&lds[b * 68 + seg * 8];
        f32x4 x1 = *(f32x4*)&lds[b * 68 + seg * 8 + 4];
        *(f32x4*)gout = x0;
        *(f32x4*)(gout + 4) = x1;
    }
}

__global__ __launch_bounds__(256) void combine_kernel(
    const float* __restrict__ gbuf,
    const float* __restrict__ bih, const float* __restrict__ bhh,
    const float* __restrict__ hprev, float* __restrict__ hnew)
{
    const int idx = blockIdx.x * 256 + threadIdx.x;   // 0..32767
    const int b = idx >> 10, i = idx & 1023;
    const float* gb0 = gbuf + (size_t)b * NR_;
    const float* gb1 = gbuf + (size_t)(B_ + b) * NR_;
    const float gir = gb0[i]         + gb1[i];
    const float giz = gb0[H_ + i]    + gb1[H_ + i];
    const float gin = gb0[2*H_ + i]  + gb1[2*H_ + i];
    const float ghr = gb0[NG_ + i]        + gb1[NG_ + i];
    const float ghz = gb0[NG_ + H_ + i]   + gb1[NG_ + H_ + i];
    const float ghn = gb0[NG_ + 2*H_ + i] + gb1[NG_ + 2*H_ + i];
    const float Sr = gir + ghr + bih[i] + bhh[i];
    const float Sz = giz + ghz + bih[H_ + i] + bhh[H_ + i];
    const float rr = 1.f / (1.f + expf(-Sr));
    const float zz = 1.f / (1.f + expf(-Sz));
    const float nn = tanhf(gin + bih[2*H_ + i] + rr * (ghn + bhh[2*H_ + i]));
    const float hp = hprev[(size_t)b * H_ + i];
    hnew[(size_t)b * H_ + i] = (1.f - zz) * nn + zz * hp;
}

// Logits: 64 vocab rows/block (grid 250), bias + nt-store + fused argmax.
__global__ __launch_bounds__(256) void logits_kernel(
    const float* __restrict__ h1, const float* __restrict__ Wout,
    const float* __restrict__ bout, float* __restrict__ out_t,
    u64* __restrict__ tokpk_t)
{
    __shared__ float lds[17408];
    const int tid = threadIdx.x;
    const int v0 = blockIdx.x * 64;
    const int k4s = tid & 15;
    const int rr  = tid >> 4;

    const float *wq0, *wq1, *wq2, *wq3;
    int dW0, dW1, dW2, dW3;
    {
        const int r0 = rr, r1 = 16 + rr, r2 = 32 + rr, r3 = 48 + rr;
        wq0 = Wout + (size_t)(v0 + r0) * H_ + k4s * 4;
        wq1 = Wout + (size_t)(v0 + r1) * H_ + k4s * 4;
        wq2 = Wout + (size_t)(v0 + r2) * H_ + k4s * 4;
        wq3 = Wout + (size_t)(v0 + r3) * H_ + k4s * 4;
        dW0 = (r0 << 6) + ((k4s ^ (r0 & 7)) << 2);
        dW1 = (r1 << 6) + ((k4s ^ (r1 & 7)) << 2);
        dW2 = (r2 << 6) + ((k4s ^ (r2 & 7)) << 2);
        dW3 = (r3 << 6) + ((k4s ^ (r3 & 7)) << 2);
    }
    const float* aq0 = h1 + (size_t)rr * H_ + k4s * 4;
    const float* aq1 = h1 + (size_t)(rr + 16) * H_ + k4s * 4;
    const int dA0 = 4096 + (rr << 6) + ((k4s ^ (rr & 7)) << 2);
    const int dA1 = 4096 + ((rr + 16) << 6) + ((k4s ^ (rr & 7)) << 2);

    float acc[8][8] = {};
    gemm_core64(wq0, wq1, wq2, wq3, aq0, aq1,
                dW0, dW1, dW2, dW3, dA0, dA1, H_ >> 6, lds, tid, acc);
    reduce_totl(lds, tid, acc);

    u64* am = (u64*)(lds + 2176);            // [32][8], after totl
    {
        const int b = tid >> 3, seg = tid & 7;
        f32x4 x0 = *(f32x4*)&lds[b * 68 + seg * 8];
        f32x4 x1 = *(f32x4*)&lds[b * 68 + seg * 8 + 4];
        f32x4 bo0 = *(const f32x4*)(bout + v0 + seg * 8);
        f32x4 bo1 = *(const f32x4*)(bout + v0 + seg * 8 + 4);
        x0 += bo0; x1 += bo1;
        __builtin_nontemporal_store(
            x0, (f32x4*)(out_t + (size_t)b * V_ + v0 + seg * 8));
        __builtin_nontemporal_store(
            x1, (f32x4*)(out_t + (size_t)b * V_ + v0 + seg * 8 + 4));
        const int vb = v0 + seg * 8;
        float vals[8] = {x0.x, x0.y, x0.z, x0.w, x1.x, x1.y, x1.z, x1.w};
        u64 best = 0ull;
        #pragma unroll
        for (int i = 0; i < 8; i++) {
            u64 p = ((u64)fkey(vals[i]) << 32)
                  | (u64)(0xFFFFFFFFu - (unsigned)(vb + i));
            best = p > best ? p : best;
        }
        am[b * 8 + seg] = best;
    }
    __syncthreads();
    if (tid < 32) {
        u64 best = 0ull;
        #pragma unroll
        for (int q = 0; q < 8; q++) {
            u64 p = am[tid * 8 + q];
            best = p > best ? p : best;
        }
        atomicMax(&tokpk_t[(size_t)tid * TPAD_], best);
    }
}

extern "C" void kernel_launch(void* const* d_in, const int* in_sizes, int n_in,
                              void* d_out, int out_size, void* d_ws, size_t ws_size,
                              hipStream_t stream) {
    const float* hidden = (const float*)d_in[0];
    const float* embed  = (const float*)d_in[1];
    const float* Wih0   = (const float*)d_in[2];
    const float* Whh0   = (const float*)d_in[3];
    const float* bih0   = (const float*)d_in[4];
    const float* bhh0   = (const float*)d_in[5];
    const float* Wih1   = (const float*)d_in[6];
    const float* Whh1   = (const float*)d_in[7];
    const float* bih1   = (const float*)d_in[8];
    const float* bhh1   = (const float*)d_in[9];
    const float* Wout   = (const float*)d_in[10];
    const float* bout   = (const float*)d_in[11];
    float* out = (float*)d_out;

    const int BH = B_ * H_;
    float* ws = (float*)d_ws;
    float* h0buf = ws;                        // [2][B][H]
    float* h1buf = ws + 2 * BH;               // [2][B][H]
    float* gbuf  = ws + 4 * BH;               // [2][B][NR_]
    u64* tokpk = (u64*)(ws + 4 * BH + 2 * B_ * NR_);  // [T][B*TPAD_]

    init_kernel<<<128, 256, 0, stream>>>(hidden, h0buf, h1buf, tokpk);

    for (int t = 0; t < T_; t++) {
        const int rp = t & 1, wp = (t + 1) & 1;
        const u64* tokprev = tokpk + (size_t)(t > 0 ? t - 1 : 0) * B_ * TPAD_;

        gemm_gru<<<192, 256, 0, stream>>>(
            Wih0, Whh0, E_, nullptr, 0, embed, tokprev, t, /*tmode=*/1,
            h0buf + (size_t)rp * BH, gbuf);
        combine_kernel<<<128, 256, 0, stream>>>(
            gbuf, bih0, bhh0, h0buf + (size_t)rp * BH, h0buf + (size_t)wp * BH);

        gemm_gru<<<192, 256, 0, stream>>>(
            Wih1, Whh1, H_, h0buf + (size_t)wp * BH, H_, embed, tokprev, 0,
            /*tmode=*/0, h1buf + (size_t)rp * BH, gbuf);
        combine_kernel<<<128, 256, 0, stream>>>(
            gbuf, bih1, bhh1, h1buf + (size_t)rp * BH, h1buf + (size_t)wp * BH);

        logits_kernel<<<250, 256, 0, stream>>>(
            h1buf + (size_t)wp * BH, Wout, bout,
            out + (size_t)t * B_ * V_, tokpk + (size_t)t * B_ * TPAD_);
    }
}